// Round 4
// baseline (5349.542 us; speedup 1.0000x reference)
//
#include <hip/hip_runtime.h>

// R18: gate-split across a 2-wave workgroup. R17 post-mortem: the allocator
// will not grant >128 arch VGPRs here (VGPR_Count pinned at 128 across
// R15/R16/R17); 208 per-wave weight floats therefore ALWAYS get parked
// (AGPR shuttle in R16: ~1060us; scratch in R17: 4060us, VALUBusy 26%).
// Design for the 128-reg wall instead: wave0 of each block holds the I
// (z-fold included) + F tables, wave1 holds G + O -- 104 weight floats per
// wave, the exact budget R15 PROVED fits in 128 VGPRs with zero spill.
//
// Per phase: each wave runs the proven pk-FMA matvec on its 2 gates
// (52 pk_fma, 13 ds_read_b128 broadcasts from its OWN hrow copy), writes
// its per-lane partial pair (mA,mB) to a parity-double-buffered LDS slot,
// ONE barrier, reads the partner pair, then both waves redundantly compute
// the LSTM2 + LSTM1 activation tail (each keeps private h2/c2/c1/hrow ->
// no second barrier; double-buffering makes write-ahead safe because a
// wave cannot pass barrier(n+1) without having finished tail(n)).
//
// Residency: 2048 blocks x 2 waves = 4096 waves = 4/SIMD exactly resident
// (8 blocks/CU) under amdgpu_waves_per_eu(4) (cap 512/4 = 128 regs).
// Per-gate accumulation order (pk lane x/y, then .x+.y) is unchanged ->
// bit-identical to R14..R17.

#define H1N  51
#define NP   26    // k-pairs: k=0..51; k=51 slot = bias (hrow[51]=1.0)
#define NQ   13    // k-quads for the b128 hrow broadcast reads
#define WAVE 64

typedef float v2f __attribute__((ext_vector_type(2)));
typedef float v4f __attribute__((ext_vector_type(4)));

#define INV_LN2   1.44269504088896340736f
#define INV_LN2X2 2.88539008177792681472f

__device__ __forceinline__ float sigmoid_s(float xs) {   // input pre-scaled by 1/ln2
    return __builtin_amdgcn_rcpf(1.0f + __builtin_amdgcn_exp2f(-xs));
}
__device__ __forceinline__ float tanh_s2(float xs2) {    // input pre-scaled by 2/ln2
    float e = __builtin_amdgcn_exp2f(xs2);
    return fmaf(-2.0f, __builtin_amdgcn_rcpf(e + 1.0f), 1.0f);
}
__device__ __forceinline__ float tanh_nat(float x) {
    return tanh_s2(x * INV_LN2X2);
}
__device__ __forceinline__ float rdlane(float v, int k) {
    return __int_as_float(__builtin_amdgcn_readlane(__float_as_int(v), k));
}

__global__ __attribute__((amdgpu_flat_work_group_size(128, 128),
                          amdgpu_waves_per_eu(4)))
void lstm_gs(const float* __restrict__ input,   // [B, T]
             const float* __restrict__ W_ih1,   // [204, 1]
             const float* __restrict__ W_hh1,   // [204, 51]
             const float* __restrict__ b_ih1,   // [204]
             const float* __restrict__ b_hh1,   // [204]
             const float* __restrict__ W_ih2,   // [4, 51]
             const float* __restrict__ W_hh2,   // [4, 1]
             const float* __restrict__ b_ih2,   // [4]
             const float* __restrict__ b_hh2,   // [4]
             float* __restrict__ out,           // [B, T+F]
             int T, int TF)
{
    const int tid = threadIdx.x;
    const int j   = tid & (WAVE - 1);
    const int wid = tid >> 6;                   // 0: I,F   1: G,O
    const bool jv = (j < H1N);
    const int jj  = jv ? j : 0;
    const float m = jv ? 1.0f : 0.0f;
    const bool isz = (j >= H1N) && (j < H1N + 4);   // z-row lanes 51..54
    const int  q   = isz ? (j - H1N) : 0;
    const float mz  = isz ? 1.0f : 0.0f;
    const float mzA = (wid == 0) ? mz : 0.0f;       // z fold lives in wave0's A
    const float s2q = (q == 2) ? INV_LN2X2 : INV_LN2;  // LSTM2 gate scale

    const int s = blockIdx.x;                   // one sequence per block

    // This wave's two gate rows: A = I or G, B = F or O.
    const int rA = (wid ? 2*H1N : 0)   + jj;
    const int rB = (wid ? 3*H1N : H1N) + jj;
    const float sA = wid ? INV_LN2X2 : INV_LN2; // G is the tanh gate
    const float sB = INV_LN2;

    __shared__ __align__(16) float hrow[2][WAVE];        // per-wave h1 copies
    __shared__ __align__(16) float xch[2][2][WAVE][2];   // [wid][parity][lane][mA,mB]
    __shared__ __align__(16) float zbs[2][4];            // [parity][q]

    // 104 weight floats in VGPRs (R15-proven budget). Bias folded into the
    // k=51 slot (hrow[51]==1.0); z-lanes of wave0 carry W_ih2 row q in A.
    v2f wA[NP], wB[NP];
#pragma unroll
    for (int kk = 0; kk < NP; ++kk) {
        const int k0 = 2*kk, k1 = k0 + 1;
        wA[kk].x = m*sA*W_hh1[rA*H1N + k0] + mzA*s2q*W_ih2[q*H1N + k0];
        wB[kk].x = m*sB*W_hh1[rB*H1N + k0];
        if (k1 < H1N) {
            wA[kk].y = m*sA*W_hh1[rA*H1N + k1] + mzA*s2q*W_ih2[q*H1N + k1];
            wB[kk].y = m*sB*W_hh1[rB*H1N + k1];
        } else {   // k1 == 51: bias slot; z-rows get 0
            wA[kk].y = m*sA*(b_ih1[rA] + b_hh1[rA]);
            wB[kk].y = m*sB*(b_ih1[rB] + b_hh1[rB]);
        }
    }
#pragma unroll
    for (int kk = 0; kk < NP; ++kk)
        asm volatile("" : "+v"(wA[kk]), "+v"(wB[kk]));   // pin: no remat

    const float wx_i = m*INV_LN2  *W_ih1[jj];
    const float wx_f = m*INV_LN2  *W_ih1[H1N + jj];
    const float wx_g = m*INV_LN2X2*W_ih1[2*H1N + jj];
    const float wx_o = m*INV_LN2  *W_ih1[3*H1N + jj];

    // LSTM2 thread-uniform scalars (SGPRs), pre-scaled.
    const float wh2_0 = INV_LN2*W_hh2[0], wh2_1 = INV_LN2*W_hh2[1];
    const float wh2_2 = INV_LN2X2*W_hh2[2], wh2_3 = INV_LN2*W_hh2[3];
    const float b2_0 = INV_LN2*(b_ih2[0] + b_hh2[0]), b2_1 = INV_LN2*(b_ih2[1] + b_hh2[1]);
    const float b2_2 = INV_LN2X2*(b_ih2[2] + b_hh2[2]), b2_3 = INV_LN2*(b_ih2[3] + b_hh2[3]);

    hrow[wid][j] = (j == H1N) ? 1.0f : 0.0f;   // h1(-1)=0; [51]=1.0 (bias)
    __syncthreads();

    float c1 = 0.0f, h2 = 0.0f, c2 = 0.0f;

    const float* __restrict__ xrow = input + (long)s * T;
    float* __restrict__ orow = out + (long)s * TF;

    float xbuf = 0.0f, obuf = 0.0f;

    // One phase: matvec(h1(n-1)) on this wave's 2 gates -> exchange ->
    // [LSTM2 step n-1] -> [finish LSTM1 step n], tail redundant per wave.
    auto phase = [&](float xin, int xmode, int do_l2, int do_fin, int tt, int p) {
        v2f aA = {0.0f, 0.0f}, aB = {0.0f, 0.0f};
#pragma unroll
        for (int kq = 0; kq < NQ; ++kq) {
            const v4f h4 = *(const v4f*)&hrow[wid][4*kq];   // ds_read_b128 bcast
            const v2f hp0 = __builtin_shufflevector(h4, h4, 0, 1);
            const v2f hp1 = __builtin_shufflevector(h4, h4, 2, 3);
            asm("v_pk_fma_f32 %0, %2, %4, %0\n\t"
                "v_pk_fma_f32 %1, %3, %4, %1"
                : "+v"(aA), "+v"(aB)
                : "v"(wA[2*kq]), "v"(wB[2*kq]), "v"(hp0));
            asm("v_pk_fma_f32 %0, %2, %4, %0\n\t"
                "v_pk_fma_f32 %1, %3, %4, %1"
                : "+v"(aA), "+v"(aB)
                : "v"(wA[2*kq+1]), "v"(wB[2*kq+1]), "v"(hp1));
        }
        const float mA = aA.x + aA.y;
        const float mB = aB.x + aB.y;

        v2f pr; pr.x = mA; pr.y = mB;
        *(v2f*)&xch[wid][p][j][0] = pr;            // ds_write_b64
        if (isz && wid == 0) zbs[p][q] = mA;       // z_q(n-1) (wave0 z-lanes)
        __syncthreads();
        const v2f mo = *(const v2f*)&xch[1 - wid][p][j][0];  // partner pair

        const float mI = wid ? mo.x : mA;
        const float mF = wid ? mo.y : mB;
        const float mG = wid ? mA   : mo.x;
        const float mO = wid ? mB   : mo.y;

        if (do_l2) {                          // LSTM2 step n-1 (wave-uniform)
            const float4 z = *(const float4*)&zbs[p][0];   // b128 bcast
            const float g2i = sigmoid_s(fmaf(wh2_0, h2, b2_0 + z.x));
            const float g2f = sigmoid_s(fmaf(wh2_1, h2, b2_1 + z.y));
            const float g2g = tanh_s2 (fmaf(wh2_2, h2, b2_2 + z.z));
            const float g2o = sigmoid_s(fmaf(wh2_3, h2, b2_3 + z.w));
            c2 = fmaf(g2f, c2, g2i * g2g);
            h2 = g2o * tanh_nat(c2);
            obuf = (j == (tt & 63)) ? h2 : obuf;   // predicated pack
        }
        if (do_fin) {                         // finish LSTM1 step n
            const float x = (xmode == 0) ? xin : h2;
            const float gi = sigmoid_s(fmaf(wx_i, x, mI));
            const float gf = sigmoid_s(fmaf(wx_f, x, mF));
            const float gg = tanh_s2 (fmaf(wx_g, x, mG));
            const float go = sigmoid_s(fmaf(wx_o, x, mO));
            c1 = fmaf(gf, c1, gi * gg);
            const float h1 = go * tanh_nat(c1);
            if (jv) hrow[wid][j] = h1;        // publish h1(n) (own copy)
        }
    };

    // ---- Prologue: iteration n=0 (no LSTM2 yet) ----
    xbuf = xrow[j];
    phase(rdlane(xbuf, 0), 0, 0, 1, 0, 0);

    // ---- Warm loop: n = 1..T-1 (x from input) ----
    for (int n = 1; n < T; ++n) {
        if ((n & 63) == 0) xbuf = xrow[n + j];
        const float x = rdlane(xbuf, n & 63);
        phase(x, 0, 1, 1, n - 1, n & 1);
        if ((n & 63) == 0 && wid == 0)
            orow[n - 64 + j] = obuf;          // flush tt = n-64..n-1
    }

    // ---- Boundary: n = T (LSTM2 for T-1; first feedback step x=h2) ----
    phase(0.0f, 1, 1, 1, T - 1, T & 1);
    if (wid == 0) orow[T - 64 + j] = obuf;    // flush tt = T-64..T-1

    // ---- Future loop: n = T+1..TF-1 (x = h2 feedback) ----
    for (int n = T + 1; n < TF; ++n)
        phase(0.0f, 1, 1, 1, n - 1, n & 1);

    // ---- Drain: n = TF (LSTM2 for TF-1 only) ----
    phase(0.0f, 1, 1, 0, TF - 1, TF & 1);
    if (wid == 0) orow[TF - 64 + j] = obuf;   // flush tt = TF-64..TF-1
}

extern "C" void kernel_launch(void* const* d_in, const int* in_sizes, int n_in,
                              void* d_out, int out_size, void* d_ws, size_t ws_size,
                              hipStream_t stream) {
    const float* input = (const float*)d_in[0];
    const float* W_ih1 = (const float*)d_in[1];
    const float* W_hh1 = (const float*)d_in[2];
    const float* b_ih1 = (const float*)d_in[3];
    const float* b_hh1 = (const float*)d_in[4];
    const float* W_ih2 = (const float*)d_in[5];
    const float* W_hh2 = (const float*)d_in[6];
    const float* b_ih2 = (const float*)d_in[7];
    const float* b_hh2 = (const float*)d_in[8];
    float* out = (float*)d_out;

    const int B  = 2048;
    const int T  = in_sizes[0] / B;      // 1024
    const int TF = out_size   / B;       // 1088

    lstm_gs<<<dim3(B), dim3(2 * WAVE), 0, stream>>>(
        input, W_ih1, W_hh1, b_ih1, b_hh1, W_ih2, W_hh2, b_ih2, b_hh2,
        out, T, TF);
}

// Round 6
// 1554.950 us; speedup vs baseline: 3.4403x; 3.4403x over previous
//
#include <hip/hip_runtime.h>

// R20: gate-split ACROSS waves x 2 sequences PER wave.
//
// Ledger driving this design:
//  - gfx950 VALU cannot source AGPRs at all (R19 assembler rejection of
//    v_fma_f32 with "a" operand; R13 same for VOP3P). AGPR-parked weights
//    cost 1 v_accvgpr_read per use per phase.
//  - Arch-VGPR grant: waves_per_eu min=1 -> ~136, min=2 -> 128, min=4 -> 64
//    (R14/R16/R18). Any design needing >~104 weight floats/wave pays ~200
//    shuttle instr/phase: R14/R15/R16 all measured ~437 instr/phase.
//  - R18 (gate-split, 104 wts/wave) was structurally right, killed only by
//    min=4 -> 64 grant -> scratch spill -> 9.3 GB refetch.
//
// Design: block = 2 waves. wave0 holds I(+z-fold)+F tables, wave1 holds
// G+O -- 104 weight floats/wave, tax-free. Weights are sequence-independent
// (R14's economy), so each wave runs the matvec for TWO sequences A,B
// (de-interleaved in one straight-line region = static ILP on top of the
// 2-waves/SIMD dynamic overlap). ONE barrier per step covers both seqs'
// partial-sum exchange (parity double-buffered slots, R18's proven
// protocol: a wave cannot pass barrier n+1 before its partner consumed
// parity-p of step n, and the next same-parity write is after barrier n+1).
// Both waves redundantly compute the LSTM2 + LSTM1 tails (keeps h-state
// private -> no second barrier).
//
// Residency: 1024 blocks x 2 waves = 2048 waves = 2/SIMD; needs only
// total regs/wave <= 256 (actual ~150) -> no occupancy cliff, no parking.
// waves_per_eu(1) (no max) lets the allocator take pressure-driven arch
// VGPRs (~150) while 2 waves/SIMD still fit the 512 unified file.
//
// Per wave-step: 2x(52 pk_fma + 13 ds_read_b128) + exchange + 2 tails
// ~= 295 instr for 2 seqs = ~147/seq-phase vs the measured 437 of
// R14/R15/R16. Numerics: per-gate pk x/y summation then .x+.y unchanged
// -> bit-identical output (absmax must stay 0.0002441406).

#define H1N  51
#define NP   26    // k-pairs: k=0..51; k=51 slot = bias (hrow[51]=1.0)
#define NQ   13    // k-quads for the b128 hrow broadcast reads
#define WAVE 64

typedef float v2f __attribute__((ext_vector_type(2)));
typedef float v4f __attribute__((ext_vector_type(4)));

#define INV_LN2   1.44269504088896340736f
#define INV_LN2X2 2.88539008177792681472f

__device__ __forceinline__ float sigmoid_s(float xs) {   // input pre-scaled by 1/ln2
    return __builtin_amdgcn_rcpf(1.0f + __builtin_amdgcn_exp2f(-xs));
}
__device__ __forceinline__ float tanh_s2(float xs2) {    // input pre-scaled by 2/ln2
    float e = __builtin_amdgcn_exp2f(xs2);
    return fmaf(-2.0f, __builtin_amdgcn_rcpf(e + 1.0f), 1.0f);
}
__device__ __forceinline__ float tanh_nat(float x) {
    return tanh_s2(x * INV_LN2X2);
}
__device__ __forceinline__ float rdlane(float v, int k) {
    return __int_as_float(__builtin_amdgcn_readlane(__float_as_int(v), k));
}

__global__ __attribute__((amdgpu_flat_work_group_size(128, 128),
                          amdgpu_waves_per_eu(1)))
void lstm_gs2(const float* __restrict__ input,   // [B, T]
              const float* __restrict__ W_ih1,   // [204, 1]
              const float* __restrict__ W_hh1,   // [204, 51]
              const float* __restrict__ b_ih1,   // [204]
              const float* __restrict__ b_hh1,   // [204]
              const float* __restrict__ W_ih2,   // [4, 51]
              const float* __restrict__ W_hh2,   // [4, 1]
              const float* __restrict__ b_ih2,   // [4]
              const float* __restrict__ b_hh2,   // [4]
              float* __restrict__ out,           // [B, T+F]
              int T, int TF)
{
    const int tid = threadIdx.x;
    const int j   = tid & (WAVE - 1);
    const int wid = tid >> 6;                   // 0: I,F   1: G,O
    const bool jv = (j < H1N);
    const int jj  = jv ? j : 0;
    const float m = jv ? 1.0f : 0.0f;
    const bool isz = (j >= H1N) && (j < H1N + 4);   // z-row lanes 51..54
    const int  q   = isz ? (j - H1N) : 0;
    const float mz  = isz ? 1.0f : 0.0f;
    const float mzA = (wid == 0) ? mz : 0.0f;       // z fold lives in wave0's A
    const float s2q = (q == 2) ? INV_LN2X2 : INV_LN2;  // LSTM2 gate scale

    const int sA = 2 * blockIdx.x, sB = sA + 1;  // two sequences per block

    // This wave's two gate rows: A = I or G, B = F or O.
    const int rA = (wid ? 2*H1N : 0)   + jj;
    const int rB = (wid ? 3*H1N : H1N) + jj;
    const float sclA = wid ? INV_LN2X2 : INV_LN2;  // G is the tanh gate
    const float sclB = INV_LN2;

    __shared__ __align__(16) float hrow[2][2][WAVE];       // [wid][seq][lane]
    __shared__ __align__(16) float xch[2][2][2][WAVE][2];  // [wid][seq][par][lane][mA,mB]
    __shared__ __align__(16) float zbs[2][2][4];           // [seq][par][q]

    // 104 weight floats in VGPRs (tax-free budget). Bias folded into the
    // k=51 slot (hrow[51]==1.0); z-lanes of wave0 carry W_ih2 row q in A.
    v2f wA[NP], wB[NP];
#pragma unroll
    for (int kk = 0; kk < NP; ++kk) {
        const int k0 = 2*kk, k1 = k0 + 1;
        wA[kk].x = m*sclA*W_hh1[rA*H1N + k0] + mzA*s2q*W_ih2[q*H1N + k0];
        wB[kk].x = m*sclB*W_hh1[rB*H1N + k0];
        if (k1 < H1N) {
            wA[kk].y = m*sclA*W_hh1[rA*H1N + k1] + mzA*s2q*W_ih2[q*H1N + k1];
            wB[kk].y = m*sclB*W_hh1[rB*H1N + k1];
        } else {   // k1 == 51: bias slot; z-rows get 0
            wA[kk].y = m*sclA*(b_ih1[rA] + b_hh1[rA]);
            wB[kk].y = m*sclB*(b_ih1[rB] + b_hh1[rB]);
        }
    }
#pragma unroll
    for (int kk = 0; kk < NP; ++kk)
        asm volatile("" : "+v"(wA[kk]), "+v"(wB[kk]));   // pin: no remat

    const float wx_i = m*INV_LN2  *W_ih1[jj];
    const float wx_f = m*INV_LN2  *W_ih1[H1N + jj];
    const float wx_g = m*INV_LN2X2*W_ih1[2*H1N + jj];
    const float wx_o = m*INV_LN2  *W_ih1[3*H1N + jj];

    // LSTM2 thread-uniform scalars (SGPRs), pre-scaled.
    const float wh2_0 = INV_LN2*W_hh2[0], wh2_1 = INV_LN2*W_hh2[1];
    const float wh2_2 = INV_LN2X2*W_hh2[2], wh2_3 = INV_LN2*W_hh2[3];
    const float b2_0 = INV_LN2*(b_ih2[0] + b_hh2[0]), b2_1 = INV_LN2*(b_ih2[1] + b_hh2[1]);
    const float b2_2 = INV_LN2X2*(b_ih2[2] + b_hh2[2]), b2_3 = INV_LN2*(b_ih2[3] + b_hh2[3]);

    hrow[wid][0][j] = (j == H1N) ? 1.0f : 0.0f;   // h1(-1)=0; [51]=1.0 (bias)
    hrow[wid][1][j] = (j == H1N) ? 1.0f : 0.0f;
    __syncthreads();

    float c1A = 0.0f, h2A = 0.0f, c2A = 0.0f;
    float c1B = 0.0f, h2B = 0.0f, c2B = 0.0f;

    const float* __restrict__ xrowA = input + (long)sA * T;
    const float* __restrict__ xrowB = input + (long)sB * T;
    float* __restrict__ orowA = out + (long)sA * TF;
    float* __restrict__ orowB = out + (long)sB * TF;

    float xbufA = 0.0f, xbufB = 0.0f, obufA = 0.0f, obufB = 0.0f;

    // Matvec on one sequence's h-row: this wave's two gates.
    auto matvec = [&](const float* __restrict__ hr, float& mA, float& mB) {
        v2f aA = {0.0f, 0.0f}, aB = {0.0f, 0.0f};
#pragma unroll
        for (int kq = 0; kq < NQ; ++kq) {
            const v4f h4 = *(const v4f*)&hr[4*kq];        // ds_read_b128 bcast
            const v2f hp0 = __builtin_shufflevector(h4, h4, 0, 1);
            const v2f hp1 = __builtin_shufflevector(h4, h4, 2, 3);
            asm("v_pk_fma_f32 %0, %2, %4, %0\n\t"
                "v_pk_fma_f32 %1, %3, %4, %1"
                : "+v"(aA), "+v"(aB)
                : "v"(wA[2*kq]), "v"(wB[2*kq]), "v"(hp0));
            asm("v_pk_fma_f32 %0, %2, %4, %0\n\t"
                "v_pk_fma_f32 %1, %3, %4, %1"
                : "+v"(aA), "+v"(aB)
                : "v"(wA[2*kq+1]), "v"(wB[2*kq+1]), "v"(hp1));
        }
        mA = aA.x + aA.y;
        mB = aB.x + aB.y;
    };

    // One step: de-interleaved matvecs for A and B -> one barrier ->
    // exchange -> [LSTM2 step n-1] -> [finish LSTM1 step n] for both,
    // tails redundant per wave. Flags compile-time at every call site.
    auto step = [&](float xA, float xB, int xmode, int do_l2, int do_fin,
                    int tt, int p) {
        float mAA, mBA, mAB, mBB;
        matvec(&hrow[wid][0][0], mAA, mBA);      // seq A
        matvec(&hrow[wid][1][0], mAB, mBB);      // seq B

        v2f prA; prA.x = mAA; prA.y = mBA;
        v2f prB; prB.x = mAB; prB.y = mBB;
        *(v2f*)&xch[wid][0][p][j][0] = prA;      // ds_write_b64
        *(v2f*)&xch[wid][1][p][j][0] = prB;
        if (isz && wid == 0) { zbs[0][p][q] = mAA; zbs[1][p][q] = mAB; }
        __syncthreads();
        const v2f moA = *(const v2f*)&xch[1 - wid][0][p][j][0];
        const v2f moB = *(const v2f*)&xch[1 - wid][1][p][j][0];

        const float mI_A = wid ? moA.x : mAA;
        const float mF_A = wid ? moA.y : mBA;
        const float mG_A = wid ? mAA   : moA.x;
        const float mO_A = wid ? mBA   : moA.y;
        const float mI_B = wid ? moB.x : mAB;
        const float mF_B = wid ? moB.y : mBB;
        const float mG_B = wid ? mAB   : moB.x;
        const float mO_B = wid ? mBB   : moB.y;

        if (do_l2) {                          // LSTM2 step n-1 (wave-uniform)
            const float4 zA = *(const float4*)&zbs[0][p][0];   // b128 bcast
            const float g2iA = sigmoid_s(fmaf(wh2_0, h2A, b2_0 + zA.x));
            const float g2fA = sigmoid_s(fmaf(wh2_1, h2A, b2_1 + zA.y));
            const float g2gA = tanh_s2 (fmaf(wh2_2, h2A, b2_2 + zA.z));
            const float g2oA = sigmoid_s(fmaf(wh2_3, h2A, b2_3 + zA.w));
            c2A = fmaf(g2fA, c2A, g2iA * g2gA);
            h2A = g2oA * tanh_nat(c2A);
            obufA = (j == (tt & 63)) ? h2A : obufA;   // predicated pack
            const float4 zB = *(const float4*)&zbs[1][p][0];
            const float g2iB = sigmoid_s(fmaf(wh2_0, h2B, b2_0 + zB.x));
            const float g2fB = sigmoid_s(fmaf(wh2_1, h2B, b2_1 + zB.y));
            const float g2gB = tanh_s2 (fmaf(wh2_2, h2B, b2_2 + zB.z));
            const float g2oB = sigmoid_s(fmaf(wh2_3, h2B, b2_3 + zB.w));
            c2B = fmaf(g2fB, c2B, g2iB * g2gB);
            h2B = g2oB * tanh_nat(c2B);
            obufB = (j == (tt & 63)) ? h2B : obufB;
        }
        if (do_fin) {                         // finish LSTM1 step n
            const float xA_ = (xmode == 0) ? xA : h2A;
            const float giA = sigmoid_s(fmaf(wx_i, xA_, mI_A));
            const float gfA = sigmoid_s(fmaf(wx_f, xA_, mF_A));
            const float ggA = tanh_s2 (fmaf(wx_g, xA_, mG_A));
            const float goA = sigmoid_s(fmaf(wx_o, xA_, mO_A));
            c1A = fmaf(gfA, c1A, giA * ggA);
            const float h1A = goA * tanh_nat(c1A);
            if (jv) hrow[wid][0][j] = h1A;    // publish h1(n) (own copy)
            const float xB_ = (xmode == 0) ? xB : h2B;
            const float giB = sigmoid_s(fmaf(wx_i, xB_, mI_B));
            const float gfB = sigmoid_s(fmaf(wx_f, xB_, mF_B));
            const float ggB = tanh_s2 (fmaf(wx_g, xB_, mG_B));
            const float goB = sigmoid_s(fmaf(wx_o, xB_, mO_B));
            c1B = fmaf(gfB, c1B, giB * ggB);
            const float h1B = goB * tanh_nat(c1B);
            if (jv) hrow[wid][1][j] = h1B;
        }
    };

    // ---- Prologue: iteration n=0 (no LSTM2 yet) ----
    xbufA = xrowA[j]; xbufB = xrowB[j];
    step(rdlane(xbufA, 0), rdlane(xbufB, 0), 0, 0, 1, 0, 0);

    // ---- Warm loop: n = 1..T-1 (x from input) ----
    for (int n = 1; n < T; ++n) {
        if ((n & 63) == 0) { xbufA = xrowA[n + j]; xbufB = xrowB[n + j]; }
        const int u = n & 63;
        step(rdlane(xbufA, u), rdlane(xbufB, u), 0, 1, 1, n - 1, n & 1);
        if ((n & 63) == 0 && wid == 0) {      // flush tt = n-64..n-1
            orowA[n - 64 + j] = obufA;
            orowB[n - 64 + j] = obufB;
        }
    }

    // ---- Boundary: n = T (LSTM2 for T-1; first feedback step x=h2) ----
    step(0.0f, 0.0f, 1, 1, 1, T - 1, T & 1);
    if (wid == 0) { orowA[T - 64 + j] = obufA; orowB[T - 64 + j] = obufB; }

    // ---- Future loop: n = T+1..TF-1 (x = h2 feedback) ----
    for (int n = T + 1; n < TF; ++n)
        step(0.0f, 0.0f, 1, 1, 1, n - 1, n & 1);

    // ---- Drain: n = TF (LSTM2 for TF-1 only) ----
    step(0.0f, 0.0f, 1, 1, 0, TF - 1, TF & 1);
    if (wid == 0) { orowA[TF - 64 + j] = obufA; orowB[TF - 64 + j] = obufB; }
}

extern "C" void kernel_launch(void* const* d_in, const int* in_sizes, int n_in,
                              void* d_out, int out_size, void* d_ws, size_t ws_size,
                              hipStream_t stream) {
    const float* input = (const float*)d_in[0];
    const float* W_ih1 = (const float*)d_in[1];
    const float* W_hh1 = (const float*)d_in[2];
    const float* b_ih1 = (const float*)d_in[3];
    const float* b_hh1 = (const float*)d_in[4];
    const float* W_ih2 = (const float*)d_in[5];
    const float* W_hh2 = (const float*)d_in[6];
    const float* b_ih2 = (const float*)d_in[7];
    const float* b_hh2 = (const float*)d_in[8];
    float* out = (float*)d_out;

    const int B  = 2048;
    const int T  = in_sizes[0] / B;      // 1024
    const int TF = out_size   / B;       // 1088

    lstm_gs2<<<dim3(B / 2), dim3(2 * WAVE), 0, stream>>>(
        input, W_ih1, W_hh1, b_ih1, b_hh1, W_ih2, W_hh2, b_ih2, b_hh2,
        out, T, TF);
}

// Round 7
// 1243.910 us; speedup vs baseline: 4.3006x; 1.2501x over previous
//
#include <hip/hip_runtime.h>

// R21: gate-split, software-pipelined tail. R20 post-mortem isolated two
// costs on top of the (correct) shuttle-free gate-split: redundant tails
// (both waves computed both seqs' trans-heavy tails) and per-access LDS
// address arithmetic (runtime wid/parity indices -> v_lshl_add chains,
// ~+460 issue-cyc/wave-step vs R16's base+imm-offset addressing).
//
// Fix: pipeline the tail one step behind the matvec:
//   iter n:  tail(n-1)  B1  matvec(n) + push partials  B2  pull partials
// Each wave tails ONLY its own seq (wave0->A, wave1->B; balanced, no
// redundancy). Cross-wave handoffs: h1 (tail->partner matvec) crosses B1;
// partials (matvec->partner tail) cross B2. xch and zbB need NO parity
// (write/read regions are barrier-separated; next write is another
// barrier later); only hrow is parity-double-buffered via one `par ^= 1`.
// All LDS accesses are single-base + compile-time offsets. z(A) bypasses
// LDS entirely (4 readlanes from wave0's own I-accumulator, z-row trick);
// z(B) crosses via 1 predicated write + 1 b128 broadcast.
//
// Ledger carried: VALU cannot source AGPRs on gfx950 (R13/R19); allocator
// grants 128 arch VGPRs at waves_per_eu(2) (R15-R17); 104 weight floats
// per wave is the proven zero-park budget (R15/R20); per-gate pk x/y
// accumulation order preserved -> bit-identical (absmax 0.0002441406).

#define H1N  51
#define NP   26    // k-pairs: k=0..51; k=51 slot = bias (hrow[51]=1.0)
#define NQ   13    // k-quads for the b128 hrow broadcast reads
#define WAVE 64

typedef float v2f __attribute__((ext_vector_type(2)));
typedef float v4f __attribute__((ext_vector_type(4)));

#define INV_LN2   1.44269504088896340736f
#define INV_LN2X2 2.88539008177792681472f

__device__ __forceinline__ float sigmoid_s(float xs) {   // input pre-scaled by 1/ln2
    return __builtin_amdgcn_rcpf(1.0f + __builtin_amdgcn_exp2f(-xs));
}
__device__ __forceinline__ float tanh_s2(float xs2) {    // input pre-scaled by 2/ln2
    float e = __builtin_amdgcn_exp2f(xs2);
    return fmaf(-2.0f, __builtin_amdgcn_rcpf(e + 1.0f), 1.0f);
}
__device__ __forceinline__ float tanh_nat(float x) {
    return tanh_s2(x * INV_LN2X2);
}
__device__ __forceinline__ float rdlane(float v, int k) {
    return __int_as_float(__builtin_amdgcn_readlane(__float_as_int(v), k));
}

__global__ __attribute__((amdgpu_flat_work_group_size(128, 128),
                          amdgpu_waves_per_eu(2)))
void lstm_pp(const float* __restrict__ input,   // [B, T]
             const float* __restrict__ W_ih1,   // [204, 1]
             const float* __restrict__ W_hh1,   // [204, 51]
             const float* __restrict__ b_ih1,   // [204]
             const float* __restrict__ b_hh1,   // [204]
             const float* __restrict__ W_ih2,   // [4, 51]
             const float* __restrict__ W_hh2,   // [4, 1]
             const float* __restrict__ b_ih2,   // [4]
             const float* __restrict__ b_hh2,   // [4]
             float* __restrict__ out,           // [B, T+F]
             int T, int TF)
{
    const int tid = threadIdx.x;
    const int j   = tid & (WAVE - 1);
    const int wid = tid >> 6;                   // 0: I,F (tails A)  1: G,O (tails B)
    const bool w0 = (wid == 0);
    const bool jv = (j < H1N);
    const int jj  = jv ? j : 0;
    const float m = jv ? 1.0f : 0.0f;
    const bool isz = (j >= H1N) && (j < H1N + 4);   // z-row lanes 51..54
    const int  q   = isz ? (j - H1N) : 0;
    const float mz  = isz ? 1.0f : 0.0f;
    const float mzA = w0 ? mz : 0.0f;               // z fold lives in wave0's A gate
    const float s2q = (q == 2) ? INV_LN2X2 : INV_LN2;  // LSTM2 gate scale

    // This wave's two gate rows: A = I or G, B = F or O.
    const int rA = (w0 ? 0 : 2*H1N)   + jj;
    const int rB = (w0 ? H1N : 3*H1N) + jj;
    const float sclA = w0 ? INV_LN2 : INV_LN2X2;    // G is the tanh gate
    const float sclB = INV_LN2;

    __shared__ __align__(16) float hrow[2][2][WAVE];   // [seq][par][lane]
    __shared__ __align__(16) float xch[2][WAVE][2];    // [seq][lane][pairA,pairB]
    __shared__ __align__(16) float zbB[4];             // z for seq B (w0 -> w1)

    // 104 weight floats in VGPRs (proven zero-park budget). Bias folded
    // into the k=51 slot (hrow[51]==1.0); wave0's z-lanes carry W_ih2.
    v2f wA[NP], wB[NP];
#pragma unroll
    for (int kk = 0; kk < NP; ++kk) {
        const int k0 = 2*kk, k1 = k0 + 1;
        wA[kk].x = m*sclA*W_hh1[rA*H1N + k0] + mzA*s2q*W_ih2[q*H1N + k0];
        wB[kk].x = m*sclB*W_hh1[rB*H1N + k0];
        if (k1 < H1N) {
            wA[kk].y = m*sclA*W_hh1[rA*H1N + k1] + mzA*s2q*W_ih2[q*H1N + k1];
            wB[kk].y = m*sclB*W_hh1[rB*H1N + k1];
        } else {   // k1 == 51: bias slot; z-rows get 0
            wA[kk].y = m*sclA*(b_ih1[rA] + b_hh1[rA]);
            wB[kk].y = m*sclB*(b_ih1[rB] + b_hh1[rB]);
        }
    }
#pragma unroll
    for (int kk = 0; kk < NP; ++kk)
        asm volatile("" : "+v"(wA[kk]), "+v"(wB[kk]));   // pin: no remat

    // x-side weights for my tail (all 4 gates, per-lane j).
    const float wx_i = m*INV_LN2  *W_ih1[jj];
    const float wx_f = m*INV_LN2  *W_ih1[H1N + jj];
    const float wx_g = m*INV_LN2X2*W_ih1[2*H1N + jj];
    const float wx_o = m*INV_LN2  *W_ih1[3*H1N + jj];

    // LSTM2 thread-uniform scalars (SGPRs), pre-scaled.
    const float wh2_0 = INV_LN2*W_hh2[0], wh2_1 = INV_LN2*W_hh2[1];
    const float wh2_2 = INV_LN2X2*W_hh2[2], wh2_3 = INV_LN2*W_hh2[3];
    const float b2_0 = INV_LN2*(b_ih2[0] + b_hh2[0]), b2_1 = INV_LN2*(b_ih2[1] + b_hh2[1]);
    const float b2_2 = INV_LN2X2*(b_ih2[2] + b_hh2[2]), b2_3 = INV_LN2*(b_ih2[3] + b_hh2[3]);

    // Init both parities: h1(-1)=0, bias lane 51 = 1.0 (never overwritten:
    // tails write only j<51), lanes 52..63 = 0.
    {
        const float e = (j == H1N) ? 1.0f : 0.0f;
        if (w0) { hrow[0][0][j] = e; hrow[0][1][j] = e; }
        else    { hrow[1][0][j] = e; hrow[1][1][j] = e; }
    }
    __syncthreads();

    const int myseq = wid;
    const float* __restrict__ xrow = input + (long)(2*blockIdx.x + myseq) * T;
    float* __restrict__ orow = out + (long)(2*blockIdx.x + myseq) * TF;

    float c1 = 0.0f, h2 = 0.0f, c2 = 0.0f, obuf = 0.0f, xbuf = 0.0f;
    float ownA = 0.0f, ownB = 0.0f, rdA = 0.0f, rdB = 0.0f;  // partial carries
    float zA0 = 0.0f, zA1 = 0.0f, zA2 = 0.0f, zA3 = 0.0f;
    float4 zB4 = {0.0f, 0.0f, 0.0f, 0.0f};

    int par = 1;   // slot matvec(0) reads (h1(-1) lives at parity (-1)&1 = 1)

    // Matvec for one seq: this wave's two gates, pk x/y order preserved.
    auto MV1 = [&](int seq, float& sA_, float& sB_) {
        v2f aA = {0.0f, 0.0f}, aB = {0.0f, 0.0f};
#pragma unroll
        for (int kq = 0; kq < NQ; ++kq) {
            const v4f h4 = *(const v4f*)&hrow[seq][par][4*kq];  // b128 bcast
            const v2f hp0 = __builtin_shufflevector(h4, h4, 0, 1);
            const v2f hp1 = __builtin_shufflevector(h4, h4, 2, 3);
            asm("v_pk_fma_f32 %0, %2, %4, %0\n\t"
                "v_pk_fma_f32 %1, %3, %4, %1"
                : "+v"(aA), "+v"(aB)
                : "v"(wA[2*kq]), "v"(wB[2*kq]), "v"(hp0));
            asm("v_pk_fma_f32 %0, %2, %4, %0\n\t"
                "v_pk_fma_f32 %1, %3, %4, %1"
                : "+v"(aA), "+v"(aB)
                : "v"(wA[2*kq+1]), "v"(wB[2*kq+1]), "v"(hp1));
        }
        sA_ = aA.x + aA.y;
        sB_ = aB.x + aB.y;
    };

    // matvec(n) for both seqs + push partner partials + B2 + pull.
    auto MVX = [&]() {
        float s0A, s0B, s1A, s1B;
        MV1(0, s0A, s0B);                      // seq A
        MV1(1, s1A, s1B);                      // seq B
        // push: partner's tail seq partials (w0 pushes seq B, w1 seq A)
        v2f pr;
        pr.x = w0 ? s1A : s0A;
        pr.y = w0 ? s1B : s0B;
        *(v2f*)&xch[w0 ? 1 : 0][j][0] = pr;    // ds_write_b64
        if (w0) {
            if (isz) zbB[q] = s1A;             // z(B) -> LDS for wave1
            zA0 = rdlane(s0A, H1N + 0);        // z(A) stays in-register
            zA1 = rdlane(s0A, H1N + 1);
            zA2 = rdlane(s0A, H1N + 2);
            zA3 = rdlane(s0A, H1N + 3);
        }
        ownA = w0 ? s0A : s1A;                 // my tail seq, my gates
        ownB = w0 ? s0B : s1B;
        __syncthreads();                       // B2: partials visible
        const v2f mo = *(const v2f*)&xch[w0 ? 0 : 1][j][0];
        rdA = mo.x; rdB = mo.y;
        if (!w0) zB4 = *(const float4*)zbB;    // b128 bcast
    };

    // Tail for my seq at step t: [LSTM2(t-1) if do_l2] + [LSTM1 fin(t) if
    // do_fin]. Consumes partials(t) carried in regs; writes h1(t) to
    // hrow[myseq][par] (the slot matvec(t+1) reads after B1).
    auto TAIL = [&](int t, int do_l2, int do_fin, int xmode) {
        const float mI = w0 ? ownA : rdA;
        const float mF = w0 ? ownB : rdB;
        const float mG = w0 ? rdA  : ownA;
        const float mO = w0 ? rdB  : ownB;

        if (do_l2) {                           // LSTM2 step t-1 (wave-uniform)
            const float zz0 = w0 ? zA0 : zB4.x;
            const float zz1 = w0 ? zA1 : zB4.y;
            const float zz2 = w0 ? zA2 : zB4.z;
            const float zz3 = w0 ? zA3 : zB4.w;
            const float g2i = sigmoid_s(fmaf(wh2_0, h2, b2_0 + zz0));
            const float g2f = sigmoid_s(fmaf(wh2_1, h2, b2_1 + zz1));
            const float g2g = tanh_s2 (fmaf(wh2_2, h2, b2_2 + zz2));
            const float g2o = sigmoid_s(fmaf(wh2_3, h2, b2_3 + zz3));
            c2 = fmaf(g2f, c2, g2i * g2g);
            h2 = g2o * tanh_nat(c2);
            obuf = (j == ((t - 1) & 63)) ? h2 : obuf;   // pack out(t-1)
            if ((t & 63) == 0) orow[t - 64 + j] = obuf; // flush t-64..t-1
        }
        if (do_fin) {                          // LSTM1 step t
            float x;
            if (xmode == 0) {
                if ((t & 63) == 0) xbuf = xrow[t + j];
                x = rdlane(xbuf, t & 63);
            } else {
                x = h2;                        // feedback
            }
            const float gi = sigmoid_s(fmaf(wx_i, x, mI));
            const float gf = sigmoid_s(fmaf(wx_f, x, mF));
            const float gg = tanh_s2 (fmaf(wx_g, x, mG));
            const float go = sigmoid_s(fmaf(wx_o, x, mO));
            c1 = fmaf(gf, c1, gi * gg);
            const float h1 = go * tanh_nat(c1);
            if (jv) hrow[myseq][par][j] = h1;  // publish h1(t)
        }
    };

    // ---- iter 0: matvec(0) only (reads h1(-1) at par=1) ----
    MVX(); par ^= 1;

    // ---- iter 1: tail(0) [no LSTM2], matvec(1) ----
    TAIL(0, 0, 1, 0);
    __syncthreads();                           // B1
    MVX(); par ^= 1;

    // ---- warm: iters n=2..T (t = 1..T-1, x from input) ----
    for (int n = 2; n <= T; ++n) {
        TAIL(n - 1, 1, 1, 0);
        __syncthreads();                       // B1: h1 visible to partner
        MVX(); par ^= 1;
    }

    // ---- future: iters n=T+1..TF (t = T..TF-1, x = h2 feedback) ----
    for (int n = T + 1; n <= TF; ++n) {
        TAIL(n - 1, 1, 1, 1);
        __syncthreads();                       // B1
        MVX(); par ^= 1;
    }

    // ---- final: LSTM2(TF-1) + last flush (no LSTM1 fin) ----
    TAIL(TF, 1, 0, 1);
}

extern "C" void kernel_launch(void* const* d_in, const int* in_sizes, int n_in,
                              void* d_out, int out_size, void* d_ws, size_t ws_size,
                              hipStream_t stream) {
    const float* input = (const float*)d_in[0];
    const float* W_ih1 = (const float*)d_in[1];
    const float* W_hh1 = (const float*)d_in[2];
    const float* b_ih1 = (const float*)d_in[3];
    const float* b_hh1 = (const float*)d_in[4];
    const float* W_ih2 = (const float*)d_in[5];
    const float* W_hh2 = (const float*)d_in[6];
    const float* b_ih2 = (const float*)d_in[7];
    const float* b_hh2 = (const float*)d_in[8];
    float* out = (float*)d_out;

    const int B  = 2048;
    const int T  = in_sizes[0] / B;      // 1024
    const int TF = out_size   / B;       // 1088

    lstm_pp<<<dim3(B / 2), dim3(2 * WAVE), 0, stream>>>(
        input, W_ih1, W_hh1, b_ih1, b_hh1, W_ih2, W_hh2, b_ih2, b_hh2,
        out, T, TF);
}